// Round 13
// baseline (532.954 us; speedup 1.0000x reference)
//
#include <hip/hip_runtime.h>

// ---------------------------------------------------------------------------
// STEncoder (STGCN-style) on MI355X.
// B=16, N=2000 (pad 2048), T=12, D_IN=3, C=64, CM=32, KS=KT=3.
// Chebyshev: T0=I, T2=2L^2-I -> 2 big GEMMs/block, k0/k2 folded into theta.
// R10 (verified): k_gemm fat tiles (160x256 / 96x256, 1 block/CU) + 4-phase
//   interleave, BK=64, dbuf, counted vmcnt. ~913 TF big-shape; staged
//   delivery ~10 TB/s = L3 ceiling. FROZEN (L^2-fusion nets ~0: checked).
// R12/R13a/R14/R15 (verified): channel-major activations, coalesced
//   k_inconv, k_mixT LDS store turn-around (-61us).
// R17 (verified, -25us): k_mix12 fusion with drain-free raw barriers.
// R18 (verified, -20us): k_lnfin folded into LN-apply kernels; k_wpack
//   widened (3)->(3,8).
// R19 (RESUBMIT -- previous round was a container-infrastructure failure,
//   kernel never measured): (a) k_mixT<TCNT>: all TCNT+2 planes loaded to
//   registers upfront (56 VGPR for TCNT=5) -> one HBM latency per block,
//   not per t; raw lgkm barriers (stores uninterrupted). (b) k_mix12 theta
//   loop: prefetch rv(t+1) during iter t (alternating reg sets, unrolled),
//   raw barriers so prefetch stays in flight.
// ---------------------------------------------------------------------------

typedef unsigned short u16;
typedef __attribute__((ext_vector_type(8))) short short8;   // 8 x bf16 frag
typedef __attribute__((ext_vector_type(4))) float floatx4;  // MFMA acc

struct __attribute__((aligned(8))) us4 { u16 v[4]; };

#define AS1 __attribute__((address_space(1)))
#define AS3 __attribute__((address_space(3)))

__device__ __forceinline__ float b2f(u16 h) {
  union { unsigned int u; float f; } v;
  v.u = ((unsigned int)h) << 16;
  return v.f;
}
__device__ __forceinline__ u16 f2b(float f) {
  union { float f; unsigned int u; } v;
  v.f = f;
  unsigned int r = (v.u + 0x7fffu + ((v.u >> 16) & 1u)) >> 16;
  return (u16)r;
}
__device__ __forceinline__ void gl_lds16(const u16* g, u16* l) {
  __builtin_amdgcn_global_load_lds((const AS1 unsigned int*)g,
                                   (AS3 unsigned int*)l, 16, 0, 0);
}
__device__ __forceinline__ us4 load4_guard(const u16* gp, int n) {
  if (n + 3 < 2000) return *(const us4*)gp;
  us4 r;
#pragma unroll
  for (int i = 0; i < 4; ++i) r.v[i] = (n + i < 2000) ? gp[i] : (u16)0;
  return r;
}
// LN stats from fused partials (inv = 1/(2000*64), same for both blocks)
__device__ __forceinline__ void ln_stats(const float* part2, int bt,
                                         float& mu, float& rs) {
  const float inv = 1.f / 128000.f;
  mu = part2[bt * 2] * inv;
  const float var = part2[bt * 2 + 1] * inv - mu * mu;
  rs = rsqrtf(var + 1e-5f);
}

// --------------------------- graph preprocessing ---------------------------

__global__ void k_deg(const float* __restrict__ graph, float* __restrict__ d) {
  const int n = blockIdx.x;
  const int tid = threadIdx.x;
  float s = 0.f;
  const float* row = graph + (size_t)n * 2000;
  for (int m4 = tid; m4 < 500; m4 += 256) {
    const float4 g = *(const float4*)(row + m4 * 4);
    s += (g.x + g.y) + (g.z + g.w);
  }
  __shared__ float red[256];
  red[tid] = s;
  __syncthreads();
  for (int st = 128; st > 0; st >>= 1) {
    if (tid < st) red[tid] += red[tid + st];
    __syncthreads();
  }
  if (tid == 0) d[n] = rsqrtf(fmaxf(red[0] + 1.f, 1e-6f));
}

__global__ void k_lap(const float* __restrict__ graph, const float* __restrict__ d,
                      u16* __restrict__ L) {
  const int m = blockIdx.x * 1024 + threadIdx.x * 4;
  const int n = blockIdx.y;
  us4 r = {{0, 0, 0, 0}};
  if (n < 2000 && m < 2000) {
    const float4 g4 = *(const float4*)(graph + (size_t)n * 2000 + m);
    const float4 d4 = *(const float4*)(d + m);
    const float dn = d[n];
    const float gv[4] = {g4.x, g4.y, g4.z, g4.w};
    const float dv[4] = {d4.x, d4.y, d4.z, d4.w};
#pragma unroll
    for (int i = 0; i < 4; ++i) {
      const float delta = (n == m + i) ? 1.f : 0.f;
      r.v[i] = f2b(delta - dn * (gv[i] + delta) * dv[i]);
    }
  }
  *(us4*)(L + (size_t)n * 2048 + m) = r;
}

// --------------------------- input 1x1 conv (channel-major out) -------------
// h0T layout: [b][12][n:2048][c:64]; n in [2000,2048) zeroed (finite pad).
__global__ __launch_bounds__(256, 4)
void k_inconv(const float* __restrict__ x, const float* __restrict__ w,
              const float* __restrict__ bias, u16* __restrict__ h0T) {
  const int n0 = blockIdx.x * 64;
  const int b = blockIdx.y / 12, t = blockIdx.y % 12;
  const int tid = threadIdx.x;
  u16* outb = h0T + ((size_t)(b * 12 + t) * 2048 + n0) * 64;
  const float* xb = x + ((size_t)(b * 3) * 12 + t) * 2000;
#pragma unroll
  for (int q = 0; q < 4; ++q) {
    const int f = q * 256 + tid;       // flat us4 index in [0,1024)
    const int nl = f >> 4;             // local n 0..63
    const int c4 = (f & 15) * 4;       // channel base
    const int n = n0 + nl;
    us4 r = {{0, 0, 0, 0}};
    if (n < 2000) {
      const float a0 = xb[n];
      const float a1 = xb[12 * 2000 + n];
      const float a2 = xb[2 * 12 * 2000 + n];
#pragma unroll
      for (int j = 0; j < 4; ++j) {
        const int o = c4 + j;
        r.v[j] = f2b(a0 * w[o] + a1 * w[64 + o] + a2 * w[128 + o] + bias[o]);
      }
    }
    *(us4*)(outb + f * 4) = r;
  }
}

// --------------------------- weight fragment packing ------------------------
// grid (3, 8) -- 8-way slice of each mode's idx space (stride 2048).
__global__ void k_wpack(const float* __restrict__ t1w, const float* __restrict__ aw,
                        const float* __restrict__ th, const float* __restrict__ t2w,
                        u16* __restrict__ wglu, u16* __restrict__ wth,
                        u16* __restrict__ wt2, float* __restrict__ part2) {
  const int mode = blockIdx.x;
  const int start = blockIdx.y * 256 + threadIdx.x;
  if (mode == 0) {  // GLU: M=64, K=192, KS=6
    for (int idx = start; idx < 1536 * 8; idx += 2048) {
      int chunk = idx >> 3, j = idx & 7;
      int l15 = chunk & 15, quad = (chunk >> 4) & 3, g = chunk >> 6;
      int ks = g % 6, mi = g / 6;
      int o = mi * 16 + l15;
      int k = ks * 32 + quad * 8 + j;
      int c = k & 63, dt = k >> 6;
      float v = t1w[(o * 64 + c) * 3 + dt];
      if (o < 32 && dt == 2) v += aw[o * 64 + c];
      wglu[idx] = f2b(v);
    }
  } else if (mode == 1) {  // theta: M=32, K=96, KS=3 (padded to 512 chunks)
    if (blockIdx.y == 0) part2[threadIdx.x] = 0.f;  // zero LN partials
    for (int idx = start; idx < 512 * 8; idx += 2048) {
      int chunk = idx >> 3, j = idx & 7;
      int l15 = chunk & 15, quad = (chunk >> 4) & 3, g = chunk >> 6;
      float v = 0.f;
      if (g < 6) {
        int ks = g % 3, mi = g / 3;
        int o = mi * 16 + l15;
        int k = ks * 32 + quad * 8 + j;
        int i = k & 31, src = k >> 5;
        const float* p = th + (i * 32 + o) * 3;
        v = (src == 0) ? (p[0] - p[2]) : (src == 1 ? p[1] : 2.f * p[2]);
      }
      wth[idx] = f2b(v);
    }
  } else {  // t2: M=64, K=96, KS=3
    for (int idx = start; idx < 768 * 8; idx += 2048) {
      int chunk = idx >> 3, j = idx & 7;
      int l15 = chunk & 15, quad = (chunk >> 4) & 3, g = chunk >> 6;
      int ks = g % 3, mi = g / 3;
      int o = mi * 16 + l15;
      int k = ks * 32 + quad * 8 + j;
      int i = k & 31, dt = k >> 5;
      wt2[idx] = f2b(t2w[(o * 32 + i) * 3 + dt]);
    }
  }
}

// --------------------------- GLU MFMA kernel (R19: upfront planes) ----------
// xT layout [b][T_in][2048][64]. All TCNT+2 planes loaded to registers once
// (2*(TCNT+2) short8); pure compute loop; raw lgkm barriers so the output
// stores never get drained by a barrier.
template <int TCNT>
__global__ __launch_bounds__(256, 3)
void k_mixT(const u16* __restrict__ xT, const u16* __restrict__ wp,
            const float* __restrict__ b0, const float* __restrict__ b1,
            u16* __restrict__ out, int T_in, int T) {
  __shared__ __align__(16) u16 lw[1536 * 8];   // 24 KB GLU A-frags
  __shared__ __align__(16) u16 lo[2][32][72];  // 9.2 KB output turn-around
  const int tid = threadIdx.x;
  const int lane = tid & 63, wave = tid >> 6;
  const int quad = lane >> 4, l15 = lane & 15;
  const int n0 = blockIdx.x * 64;
  const int b = blockIdx.y;
  const int t0 = blockIdx.z * TCNT;

#pragma unroll
  for (int p = 0; p < 6; ++p)
    gl_lds16(wp + (size_t)(p * 256 + wave * 64 + lane) * 8,
             &lw[(p * 256 + wave * 64) * 8]);

  float svb[8], gtb[8];
#pragma unroll
  for (int mi = 0; mi < 2; ++mi)
#pragma unroll
    for (int r = 0; r < 4; ++r) {
      const int i = mi * 16 + quad * 4 + r;
      svb[mi * 4 + r] = b0[i] + b1[i];
      gtb[mi * 4 + r] = b0[32 + i];
    }

  const int n = n0 + wave * 16 + l15;
  const size_t PL = (size_t)2048 * 64;   // plane stride
  const u16* px = xT + ((size_t)(b * T_in + t0) * 2048 + n) * 64 + quad * 8;

  // upfront: ALL planes t0 .. t0+TCNT+1 -> registers (one latency exposure)
  short8 f[2 * (TCNT + 2)];
#pragma unroll
  for (int p = 0; p < TCNT + 2; ++p) {
    f[2 * p]     = *(const short8*)(px + (size_t)p * PL);
    f[2 * p + 1] = *(const short8*)(px + (size_t)p * PL + 32);
  }

  // readback indices (per thread): channel tid>>3, n-octet (tid&7)*8
  const int rch = tid >> 3;
  const int rn8 = (tid & 7) * 8;

  asm volatile("s_waitcnt vmcnt(0)" ::: "memory");   // weight DMAs + planes
  __syncthreads();

#pragma unroll
  for (int tt = 0; tt < TCNT; ++tt) {
    const int t = t0 + tt;
    floatx4 acc[4] = {};
#pragma unroll
    for (int ks = 0; ks < 6; ++ks)
#pragma unroll
      for (int mi = 0; mi < 4; ++mi) {
        short8 afr = *(const short8*)&lw[((mi * 6 + ks) * 64 + lane) * 8];
        acc[mi] = __builtin_amdgcn_mfma_f32_16x16x32_bf16(
            afr, f[2 * tt + ks], acc[mi], 0, 0, 0);
      }

    // GLU epilogue -> LDS tile
    u16(*lob)[72] = lo[tt & 1];
#pragma unroll
    for (int mi = 0; mi < 2; ++mi)
#pragma unroll
      for (int r = 0; r < 4; ++r) {
        const int i = mi * 16 + quad * 4 + r;
        const float sv = acc[mi][r] + svb[mi * 4 + r];
        const float gt = acc[mi + 2][r] + gtb[mi * 4 + r];
        const float val = sv / (1.f + __expf(-gt));
        lob[i][wave * 16 + l15] = f2b(val);
      }
    // raw barrier: lob visible; in-flight global stores NOT drained
    asm volatile("s_waitcnt lgkmcnt(0)" ::: "memory");
    asm volatile("s_barrier" ::: "memory");

    // coalesced store: 8 lanes/channel -> 128B contiguous, line-aligned
    *(short8*)(out + (size_t)((b * 32 + rch) * T + t) * 2048 + n0 + rn8) =
        *(const short8*)&lob[rch][rn8];
  }
}

// --------------------------- fused theta + t2 kernel ------------------------
// R17 fusion + R19 theta-phase prefetch: rv(t+1) issued during iter t
// (alternating reg sets, fully unrolled); raw lgkm barriers keep the
// prefetch loads in flight across barriers.
template <int TG, int TO>
__global__ __launch_bounds__(256, 2)
void k_mix12(const u16* __restrict__ x0, const u16* __restrict__ y1,
             const u16* __restrict__ y2, const u16* __restrict__ wth,
             const u16* __restrict__ wt2, const float* __restrict__ sb,
             const float* __restrict__ t2b, u16* __restrict__ out,
             float* __restrict__ part2) {
  __shared__ __align__(16) u16 lw1[512 * 8];        //  8 KB theta A-frags
  __shared__ __align__(16) u16 lw2[768 * 8];        // 12 KB t2 A-frags
  __shared__ __align__(16) u16 lx[780 * 8];         // 12 KB staging / t2-out
  __shared__ __align__(16) u16 lt[10 * 260 * 8];    // 41 KB theta-out ring
  __shared__ float redf[4][2 * TO];

  const int tid = threadIdx.x;
  const int lane = tid & 63, wave = tid >> 6;
  const int quad = lane >> 4, l15 = lane & 15;
  const int n0 = blockIdx.x * 64;
  const int b = blockIdx.y;
  const int n = n0 + wave * 16 + l15;

#pragma unroll
  for (int p = 0; p < 2; ++p)
    gl_lds16(wth + (size_t)(p * 256 + wave * 64 + lane) * 8,
             &lw1[(p * 256 + wave * 64) * 8]);
#pragma unroll
  for (int p = 0; p < 3; ++p)
    gl_lds16(wt2 + (size_t)(p * 256 + wave * 64 + lane) * 8,
             &lw2[(p * 256 + wave * 64) * 8]);

  const int nloc = (tid & 15) * 4;      // TPR=16
  const int g16 = tid >> 4;             // 0..15 row-groups per pass

  auto loadrv = [&](int t, us4 (&rv)[2][4]) {
#pragma unroll
    for (int p = 0; p < 2; ++p) {
      const int k4 = p * 16 + g16;
      if (k4 < 24) {
#pragma unroll
        for (int i = 0; i < 4; ++i) {
          const int k = k4 * 4 + i;
          const u16* base = (k < 32) ? x0 : ((k < 64) ? y1 : y2);
          rv[p][i] = *(const us4*)(base +
              (size_t)((b * 32 + (k & 31)) * TG + t) * 2048 + n0 + nloc);
        }
      }
    }
  };
  auto repack = [&](const us4 (&rv)[2][4]) {
#pragma unroll
    for (int p = 0; p < 2; ++p) {
      const int k4 = p * 16 + g16;
      if (k4 < 24) {
        const int ks = k4 >> 3, q8 = k4 & 7;
        const int quadw = (q8 >> 1) & 3;
        const int j0 = (q8 & 1) * 4;
#pragma unroll
        for (int i = 0; i < 4; ++i) {
          const int nn = nloc + i;
          const int chunk = (ks * 4 + (nn >> 4)) * 65 + quadw * 16 + (nn & 15);
          us4 wv;
          wv.v[0] = rv[p][0].v[i]; wv.v[1] = rv[p][1].v[i];
          wv.v[2] = rv[p][2].v[i]; wv.v[3] = rv[p][3].v[i];
          *(us4*)&lx[chunk * 8 + j0] = wv;
        }
      }
    }
  };

  us4 rvA[2][4], rvB[2][4];
  loadrv(0, rvA);   // issued after weight DMAs: in-order vmcnt retirement
                    // means the wait for rvA also retires the lw DMAs.
#pragma unroll
  for (int t = 0; t < TG; ++t) {
    if (t & 1) repack(rvB); else repack(rvA);
    if (t + 1 < TG) {          // prefetch next t (stays in flight: raw bars)
      if (t & 1) loadrv(t + 1, rvA); else loadrv(t + 1, rvB);
    }
    // B1: lx visible to all waves (no vmcnt drain)
    asm volatile("s_waitcnt lgkmcnt(0)" ::: "memory");
    asm volatile("s_barrier" ::: "memory");

    floatx4 acc[2] = {};
#pragma unroll
    for (int ks = 0; ks < 3; ++ks) {
      short8 bfr = *(const short8*)&lx[((ks * 4 + wave) * 65 + lane) * 8];
#pragma unroll
      for (int mi = 0; mi < 2; ++mi) {
        short8 afr = *(const short8*)&lw1[((mi * 3 + ks) * 64 + lane) * 8];
        acc[mi] = __builtin_amdgcn_mfma_f32_16x16x32_bf16(afr, bfr, acc[mi], 0, 0, 0);
      }
    }
#pragma unroll
    for (int mi = 0; mi < 2; ++mi)
#pragma unroll
      for (int r = 0; r < 4; ++r) {
        const int o = mi * 16 + quad * 4 + r;
        const float v = acc[mi][r] + sb[o] +
            b2f(lx[(wave * 65 + ((o >> 3) & 3) * 16 + l15) * 8 + (o & 7)]);
        lt[((t * 4 + wave) * 65 + ((o >> 3) & 3) * 16 + l15) * 8 + (o & 7)] =
            f2b(fmaxf(v, 0.f));
      }
    // B2: this thread's lx reads retired before next iter's repack overwrite
    asm volatile("s_waitcnt lgkmcnt(0)" ::: "memory");
    asm volatile("s_barrier" ::: "memory");
  }
  __syncthreads();  // theta done: lt complete; lo can reuse lx

  u16(*lo)[72] = (u16(*)[72])lx;        // reuse lx: 64 x 72 = 4608 <= 6240
  float sAcc[TO], ssAcc[TO];
#pragma unroll
  for (int to = 0; to < TO; ++to) { sAcc[to] = 0.f; ssAcc[to] = 0.f; }

#pragma unroll
  for (int to = 0; to < TO; ++to) {
    floatx4 acc[4] = {};
#pragma unroll
    for (int ks = 0; ks < 3; ++ks) {
      short8 bfr = *(const short8*)&lt[(((to + ks) * 4 + wave) * 65 + lane) * 8];
#pragma unroll
      for (int mi = 0; mi < 4; ++mi) {
        short8 afr = *(const short8*)&lw2[((mi * 3 + ks) * 64 + lane) * 8];
        acc[mi] = __builtin_amdgcn_mfma_f32_16x16x32_bf16(afr, bfr, acc[mi], 0, 0, 0);
      }
    }
    // epilogue -> LDS tile + in-register LN partial sums (rounded values)
#pragma unroll
    for (int mi = 0; mi < 4; ++mi)
#pragma unroll
      for (int r = 0; r < 4; ++r) {
        const int o = mi * 16 + quad * 4 + r;
        float v = acc[mi][r] + t2b[o];
        if (o < 32)
          v += b2f(lt[(((to + 2) * 4 + wave) * 65 +
                       ((o >> 3) & 3) * 16 + l15) * 8 + (o & 7)]);
        const u16 hv = f2b(fmaxf(v, 0.f));
        lo[o][wave * 16 + l15] = hv;
        if (n < 2000) {
          const float vq = b2f(hv);
          sAcc[to] += vq; ssAcc[to] += vq * vq;
        }
      }
    // B1: lo visible to all waves (LDS only -- global stores NOT drained)
    asm volatile("s_waitcnt lgkmcnt(0)" ::: "memory");
    asm volatile("s_barrier" ::: "memory");

    // coalesced store: 2 short8 per thread, 128B contiguous per channel row
#pragma unroll
    for (int q = 0; q < 2; ++q) {
      const int f = q * 256 + tid;
      const int ch = f >> 3;
      const int n8 = (f & 7) * 8;
      if (n0 + n8 < 2000)   // 2000 % 8 == 0: short8 fully in or out
        *(short8*)(out + (size_t)((b * 64 + ch) * TO + to) * 2000 + n0 + n8) =
            *(const short8*)&lo[ch][n8];
    }
    // B2: lo reads retired (lgkm) before next iter overwrites; stores fly on
    asm volatile("s_waitcnt lgkmcnt(0)" ::: "memory");
    asm volatile("s_barrier" ::: "memory");
  }

  // final LN reduction: wave shuffle -> LDS -> one atomicAdd per (to,comp)
#pragma unroll
  for (int to = 0; to < TO; ++to) {
    float s = sAcc[to], ss = ssAcc[to];
#pragma unroll
    for (int off = 32; off > 0; off >>= 1) {
      s += __shfl_down(s, off);
      ss += __shfl_down(ss, off);
    }
    if (lane == 0) { redf[wave][to * 2] = s; redf[wave][to * 2 + 1] = ss; }
  }
  __syncthreads();
  if (tid < 2 * TO) {
    atomicAdd(&part2[(b * TO + (tid >> 1)) * 2 + (tid & 1)],
              redf[0][tid] + redf[1][tid] + redf[2][tid] + redf[3][tid]);
  }
}

// --------------------------- bf16 MFMA GEMM (C = A * Bt^T) ------------------
// R10 FROZEN.
template <int BM, int MPAD, int DPW>
__global__ __launch_bounds__(512, 1)
void k_gemm(const u16* __restrict__ A, const u16* __restrict__ Bt,
            u16* __restrict__ C) {
  constexpr int K = 2048;
  constexpr int NTI = K / 64;      // 32 K-tiles
  constexpr int AFR = BM / 32;     // A frags per wave (5 or 3)
  constexpr int WM = BM / 2;       // wave M extent (80 or 48)
  constexpr int S1 = (AFR + 1) / 2;
  constexpr int C1 = DPW - 4;      // tail chunk (3 or 2)
  constexpr int BROWS = 512;       // 2 ksub * 256 B-rows
  constexpr int ROWS = BROWS + 2 * MPAD;
  __shared__ __align__(16) u16 lds[2][ROWS * 32];

  const int tid = threadIdx.x;
  const int lane = tid & 63, wave = tid >> 6;
  const int quad = lane >> 4, l15 = lane & 15;
  const int m0 = blockIdx.y * BM, n0 = blockIdx.x * 256;
  const int wy = wave >> 2, wx = wave & 3;

  const int lr = lane >> 2;
  const int qv = (((lane & 3) - (lr + (lr >> 2))) & 3);
  const u16* sp[DPW];
  int dofs[DPW];
#pragma unroll
  for (int d = 0; d < DPW; ++d) {
    const int f = wave * DPW + d;
    if (f < 32) {  // B entry
      const int rb = f >> 1, ks = f & 1;
      sp[d] = Bt + (size_t)(n0 + rb * 16 + lr) * K + ks * 32 + qv * 8;
      dofs[d] = (ks * 256 + rb * 16) * 32;
    } else {       // A entry
      const int g = f - 32;
      const int rb = g >> 1, ks = g & 1;
      sp[d] = A + (size_t)(m0 + rb * 16 + lr) * K + ks * 32 + qv * 8;
      dofs[d] = (BROWS + ks * MPAD + rb * 16) * 32;
    }
  }

  const int sigr = (l15 + (l15 >> 2)) & 3;
  const int cofs = ((quad + sigr) & 3) * 8;

  floatx4 acc[AFR][4] = {};

#pragma unroll
  for (int d = 0; d < DPW; ++d) gl_lds16(sp[d], &lds[0][dofs[d]]);
#pragma unroll
  for (int d = 0; d < C1; ++d) gl_lds16(sp[d] + 64, &lds[1][dofs[d]]);
  if constexpr (C1 == 3) asm volatile("s_waitcnt vmcnt(3)" ::: "memory");
  else                   asm volatile("s_waitcnt vmcnt(2)" ::: "memory");
  asm volatile("s_barrier" ::: "memory");

  for (int it = 0; it < NTI; ++it) {
    const u16* cb = lds[it & 1];
    u16* nb = lds[(it & 1) ^ 1];
    u16* pb = lds[it & 1];
    const int kn1 = (it + 1) * 64;
    const bool st1 = (it + 1 < NTI);
    short8 bf[4], af[AFR];

    // ---- P1: ksub0, mi [0,S1) ----
#pragma unroll
    for (int ni = 0; ni < 4; ++ni)
      bf[ni] = *(const short8*)&cb[(wx * 64 + ni * 16 + l15) * 32 + cofs];
#pragma unroll
    for (int mi = 0; mi < S1; ++mi)
      af[mi] = *(const short8*)&cb[(BROWS + wy * WM + mi * 16 + l15) * 32 + cofs];
    if (st1) {
      gl_lds16(sp[C1] + kn1, &nb[dofs[C1]]);
      gl_lds16(sp[C1 + 1] + kn1, &nb[dofs[C1 + 1]]);
    }
#pragma unroll
    for (int mi = 0; mi < S1; ++mi)
#pragma unroll
      for (int ni = 0; ni < 4; ++ni)
        acc[mi][ni] = __builtin_amdgcn_mfma_f32_16x16x32_bf16(
            af[mi], bf[ni], acc[mi][ni], 0, 0, 0);

    // ---- P2: ksub0, mi [S1,AFR) ----
#pragma unroll
    for (int mi = S1; mi < AFR; ++mi)
      af[mi] = *(const short8*)&cb[(BROWS + wy * WM + mi * 16 + l15) * 32 + cofs];
    if (st1) {
      gl_lds16(sp[C1 + 2] + kn1, &nb[dofs[C1 + 2]]);
      gl_lds16(sp[C1 + 3] + kn1, &nb[dofs[C1 + 3]]);
    }
#pragma unroll
    for (int mi = S1; mi < AFR; ++mi)
#pragma unroll
      for (int ni = 0; ni < 4; ++ni)
        acc[mi][ni] = __builtin_amdgcn_mfma_f32_16x16x32_bf16(
            af[mi], bf[ni], acc[mi][ni], 0, 0, 0);

    // ---- P3: ksub1, mi [0,S1) ----
#pragma unroll
    for (int ni = 0; ni < 4; ++ni)
      bf[ni] = *(const short8*)&cb[(256 + wx * 64 + ni * 16 + l15) * 32 + cofs];
#pragma unroll
    for (int mi = 0; mi < S1; ++mi)
      af[mi] = *(const short8*)&cb[(BROWS + MPAD + wy * WM + mi * 16 + l15) * 32 + cofs];
#pragma unroll
    for (int mi = 0; mi < S1; ++mi)
#pragma unroll
      for (int ni = 0; ni < 4; ++ni)
        acc[mi][ni] = __builtin_amdgcn_mfma_f32_16x16x32_bf16(
            af[mi], bf[ni], acc[mi][ni], 0, 0, 0);

    // ---- P4: ksub1, mi [S1,AFR) ----
#pragma unroll
    for (int mi = S1; mi < AFR; ++mi)
      af[mi] = *(const short8*)&cb[(BROWS + MPAD + wy * WM + mi * 16 + l15) * 32 + cofs];
#pragma unroll
    for (int mi = S1; mi < AFR; ++mi)
#pragma unroll
      for (int ni = 0; ni < 4; ++ni)
        acc[mi][ni] = __builtin_amdgcn_mfma_f32_16x16x32_bf16(
            af[mi], bf[ni], acc[mi][ni], 0, 0, 0);

    // ---- tail: free cb, prefetch chunk1(it+2), retire tile it+1 ----
    asm volatile("s_waitcnt lgkmcnt(0)" ::: "memory");
    asm volatile("s_barrier" ::: "memory");
    if (it + 2 < NTI) {
      const int kn2 = (it + 2) * 64;
#pragma unroll
      for (int d = 0; d < C1; ++d) gl_lds16(sp[d] + kn2, &pb[dofs[d]]);
      if constexpr (C1 == 3) asm volatile("s_waitcnt vmcnt(3)" ::: "memory");
      else                   asm volatile("s_waitcnt vmcnt(2)" ::: "memory");
    } else {
      asm volatile("s_waitcnt vmcnt(0)" ::: "memory");
    }
    asm volatile("s_barrier" ::: "memory");
  }

#pragma unroll
  for (int mi = 0; mi < AFR; ++mi) {
#pragma unroll
    for (int ni = 0; ni < 4; ++ni) {
      const int row = m0 + wy * WM + mi * 16 + quad * 4;
      const int col = n0 + wx * 64 + ni * 16 + l15;
#pragma unroll
      for (int r = 0; r < 4; ++r)
        C[(size_t)(row + r) * K + col] = f2b(acc[mi][ni][r]);
    }
  }
}

// --------------------------- LayerNorm --------------------------------------

// LN-apply + transpose to channel-major: h [b,c,T,2000] -> hT [b,T,2048,64].
// Stats computed inline from part2 (k_lnfin folded in).
__global__ __launch_bounds__(256, 4)
void k_lnapT(const u16* __restrict__ h, const float* __restrict__ part2,
             const float* __restrict__ gw, const float* __restrict__ gb,
             u16* __restrict__ hT, int T) {
  __shared__ u16 tile[64][72];
  const int tid = threadIdx.x;
  const int n0 = blockIdx.x * 64;
  const int bt = blockIdx.y;           // b*T + t
  const int b = bt / T, t = bt % T;
  float mu, rs;
  ln_stats(part2, bt, mu, rs);

  {  // coalesced read: thread -> (c = tid>>2, 16 n's)
    const int c = tid >> 2;
    const int nq = (tid & 3) * 16;
    const u16* row = h + (size_t)((b * 64 + c) * T + t) * 2000 + n0 + nq;
#pragma unroll
    for (int k = 0; k < 4; ++k) {
      const us4 v = load4_guard(row + k * 4, n0 + nq + k * 4);
      *(us4*)&tile[c][nq + k * 4] = v;
    }
  }
  __syncthreads();

  // coalesced write: thread -> (n = tid>>2, 16 c's)
  const int n = tid >> 2;
  const int c0 = (tid & 3) * 16;
  const int gn = n0 + n;
  u16* dst = hT + ((size_t)(b * T + t) * 2048 + gn) * 64 + c0;
  if (gn >= 2000) {
    const us4 z = {{0, 0, 0, 0}};
#pragma unroll
    for (int q = 0; q < 4; ++q) *(us4*)(dst + q * 4) = z;
    return;
  }
#pragma unroll
  for (int q = 0; q < 4; ++q) {
    us4 r;
#pragma unroll
    for (int j = 0; j < 4; ++j) {
      const int cc = c0 + q * 4 + j;
      const float gv = gw[(size_t)gn * 64 + cc];
      const float bv = gb[(size_t)gn * 64 + cc];
      r.v[j] = f2b((b2f(tile[cc][n]) - mu) * rs * gv + bv);
    }
    *(us4*)(dst + q * 4) = r;
  }
}

// transpose gamma/beta [2000,64] -> [64,2048] (pad zeros) -- blk1 f32 path
__global__ void k_lngbT(const float* __restrict__ gw, const float* __restrict__ gb,
                        float* __restrict__ gwT, float* __restrict__ gbT) {
  const int n = blockIdx.x * 256 + threadIdx.x;
  const int c = blockIdx.y;
  float vw = 0.f, vb = 0.f;
  if (n < 2000) {
    vw = gw[(size_t)n * 64 + c];
    vb = gb[(size_t)n * 64 + c];
  }
  gwT[(size_t)c * 2048 + n] = vw;
  gbT[(size_t)c * 2048 + n] = vb;
}

// final f32 output LN-apply (blk1 only). Stats inline from part2.
__global__ void k_lnapply(const u16* __restrict__ h, const float* __restrict__ part2,
                          const float* __restrict__ gwT, const float* __restrict__ gbT,
                          float* __restrict__ outf, int T) {
  const int n = blockIdx.x * 1024 + threadIdx.x * 4;
  if (n >= 2000) return;
  int by = blockIdx.y;
  const int t = by % T; by /= T;
  const int c = by & 63;
  const int b = by >> 6;
  float mu, rs;
  ln_stats(part2, b * T + t, mu, rs);
  const size_t row = (size_t)((b * 64 + c) * T + t) * 2000 + n;
  const us4 hv = *(const us4*)(h + row);
  const float4 w4 = *(const float4*)(gwT + (size_t)c * 2048 + n);
  const float4 b4 = *(const float4*)(gbT + (size_t)c * 2048 + n);
  const float o0 = (b2f(hv.v[0]) - mu) * rs * w4.x + b4.x;
  const float o1 = (b2f(hv.v[1]) - mu) * rs * w4.y + b4.y;
  const float o2 = (b2f(hv.v[2]) - mu) * rs * w4.z + b4.z;
  const float o3 = (b2f(hv.v[3]) - mu) * rs * w4.w + b4.w;
  *(float4*)(outf + row) = make_float4(o0, o1, o2, o3);
}

// --------------------------- launch -----------------------------------------

extern "C" void kernel_launch(void* const* d_in, const int* in_sizes, int n_in,
                              void* d_out, int out_size, void* d_ws, size_t ws_size,
                              hipStream_t stream) {
  const float* x     = (const float*)d_in[0];
  const float* graph = (const float*)d_in[1];
  const float* in_w  = (const float*)d_in[2];
  const float* in_b  = (const float*)d_in[3];

  char* ws = (char*)d_ws;
  size_t off = 0;
  auto alloc = [&](size_t bytes) -> void* {
    void* p = ws + off;
    off += (bytes + 255) & ~(size_t)255;
    return p;
  };
  float* dd    = (float*)alloc(2048 * 4);
  float* part2 = (float*)alloc(256 * 4);
  float* gwT   = (float*)alloc((size_t)64 * 2048 * 4);
  float* gbT   = (float*)alloc((size_t)64 * 2048 * 4);
  u16* wpg  = (u16*)alloc((size_t)1536 * 8 * 2);
  u16* wpt  = (u16*)alloc((size_t)512 * 8 * 2);
  u16* wp2  = (u16*)alloc((size_t)768 * 8 * 2);
  u16* L    = (u16*)alloc((size_t)2048 * 2048 * 2);
  u16* h0T  = (u16*)alloc((size_t)16 * 12 * 2048 * 64 * 2);  // channel-major
  u16* Xp   = (u16*)alloc((size_t)5120 * 2048 * 2);
  u16* Y1   = (u16*)alloc((size_t)5120 * 2048 * 2);
  u16* Y2   = (u16*)alloc((size_t)5120 * 2048 * 2);
  u16* h1   = (u16*)alloc((size_t)16 * 64 * 8 * 2000 * 2);
  u16* h1T  = h0T;  // reuse: h0T dead after blk0 k_mixT (needs 16*8*2048*64*2)
  if (off > ws_size) return;

  k_deg<<<dim3(2000), dim3(256), 0, stream>>>(graph, dd);
  k_lap<<<dim3(2, 2048), dim3(256), 0, stream>>>(graph, dd, L);
  k_inconv<<<dim3(32, 192), dim3(256), 0, stream>>>(x, in_w, in_b, h0T);

  for (int blk = 0; blk < 2; ++blk) {
    const int base = 4 + blk * 10;
    const float* t1w = (const float*)d_in[base + 0];
    const float* t1b = (const float*)d_in[base + 1];
    const float* aw  = (const float*)d_in[base + 2];
    const float* ab  = (const float*)d_in[base + 3];
    const float* th  = (const float*)d_in[base + 4];
    const float* sb  = (const float*)d_in[base + 5];
    const float* t2w = (const float*)d_in[base + 6];
    const float* t2b = (const float*)d_in[base + 7];
    const float* lng = (const float*)d_in[base + 8];
    const float* lnb = (const float*)d_in[base + 9];

    const int T_in = (blk == 0) ? 12 : 8;
    const int T_g  = T_in - 2;  // 10 / 6
    const int T_o  = T_g - 2;   // 8 / 4
    const u16* hinT = (blk == 0) ? h0T : h1T;

    k_wpack<<<dim3(3, 8), dim3(256), 0, stream>>>(t1w, aw, th, t2w, wpg, wpt,
                                                  wp2, part2);
    if (blk == 0) {
      k_mixT<5><<<dim3(32, 16, 2), dim3(256), 0, stream>>>(
          hinT, wpg, t1b, ab, Xp, T_in, T_g);
      // M = 5120 = 32 x 160
      k_gemm<160, 192, 7><<<dim3(8, 32), dim3(512), 0, stream>>>(Xp, L, Y1);
      k_gemm<160, 192, 7><<<dim3(8, 32), dim3(512), 0, stream>>>(Y1, L, Y2);
      k_mix12<10, 8><<<dim3(32, 16), dim3(256), 0, stream>>>(
          Xp, Y1, Y2, wpt, wp2, sb, t2b, h1, part2);
      // LN-apply + transpose -> channel-major input for blk1 (stats inline)
      k_lnapT<<<dim3(32, 16 * T_o), dim3(256), 0, stream>>>(
          h1, part2, lng, lnb, h1T, T_o);
    } else {
      k_mixT<3><<<dim3(32, 16, 2), dim3(256), 0, stream>>>(
          hinT, wpg, t1b, ab, Xp, T_in, T_g);
      // M = 3072 = 32 x 96
      k_gemm<96, 128, 6><<<dim3(8, 32), dim3(512), 0, stream>>>(Xp, L, Y1);
      k_gemm<96, 128, 6><<<dim3(8, 32), dim3(512), 0, stream>>>(Y1, L, Y2);
      k_mix12<6, 4><<<dim3(32, 16), dim3(256), 0, stream>>>(
          Xp, Y1, Y2, wpt, wp2, sb, t2b, h1, part2);
      k_lngbT<<<dim3(8, 64), dim3(256), 0, stream>>>(lng, lnb, gwT, gbT);
      k_lnapply<<<dim3(2, 16 * 64 * T_o), dim3(256), 0, stream>>>(
          h1, part2, gwT, gbT, (float*)d_out, T_o);
    }
  }
}

// Round 14
// 407.040 us; speedup vs baseline: 1.3093x; 1.3093x over previous
//
#include <hip/hip_runtime.h>

// ---------------------------------------------------------------------------
// STEncoder (STGCN-style) on MI355X.
// B=16, N=2000 (pad 2048), T=12, D_IN=3, C=64, CM=32, KS=KT=3.
// Chebyshev: T0=I, T2=2L^2-I -> 2 big GEMMs/block, k0/k2 folded into theta.
// R10 (verified): k_gemm fat tiles (160x256 / 96x256, 1 block/CU) + 4-phase
//   interleave, BK=64, dbuf, counted vmcnt. ~913 TF big-shape. FROZEN.
// R12-R18 (verified, 539->407.5): channel-major activations, coalesced
//   stores, LDS store turn-arounds, LN fusion w/ drain-free barriers,
//   dispatch folding.
// R19a (KEPT, unmeasured in isolation): k_mixT<TCNT> upfront-plane loads
//   (one HBM latency per block; occupancy-bound 1-shot kernel).
// R19b (REVERTED, -- measured 98us/dispatch, 3x regression): k_mix12 theta
//   prefetch + full TG unroll. All-pipes-idle signature (MfmaUtil 2%,
//   VALU 12%, HBM 10%) = code-size/front-end serialization from 10x
//   unrolling a large body; theta loads were already TLP-hidden
//   (regime-gate violation: latency fix applied to non-latency-bound
//   phase). k_mix12 restored to R18-exact form.
// ---------------------------------------------------------------------------

typedef unsigned short u16;
typedef __attribute__((ext_vector_type(8))) short short8;   // 8 x bf16 frag
typedef __attribute__((ext_vector_type(4))) float floatx4;  // MFMA acc

struct __attribute__((aligned(8))) us4 { u16 v[4]; };

#define AS1 __attribute__((address_space(1)))
#define AS3 __attribute__((address_space(3)))

__device__ __forceinline__ float b2f(u16 h) {
  union { unsigned int u; float f; } v;
  v.u = ((unsigned int)h) << 16;
  return v.f;
}
__device__ __forceinline__ u16 f2b(float f) {
  union { float f; unsigned int u; } v;
  v.f = f;
  unsigned int r = (v.u + 0x7fffu + ((v.u >> 16) & 1u)) >> 16;
  return (u16)r;
}
__device__ __forceinline__ void gl_lds16(const u16* g, u16* l) {
  __builtin_amdgcn_global_load_lds((const AS1 unsigned int*)g,
                                   (AS3 unsigned int*)l, 16, 0, 0);
}
__device__ __forceinline__ us4 load4_guard(const u16* gp, int n) {
  if (n + 3 < 2000) return *(const us4*)gp;
  us4 r;
#pragma unroll
  for (int i = 0; i < 4; ++i) r.v[i] = (n + i < 2000) ? gp[i] : (u16)0;
  return r;
}
// LN stats from fused partials (inv = 1/(2000*64), same for both blocks)
__device__ __forceinline__ void ln_stats(const float* part2, int bt,
                                         float& mu, float& rs) {
  const float inv = 1.f / 128000.f;
  mu = part2[bt * 2] * inv;
  const float var = part2[bt * 2 + 1] * inv - mu * mu;
  rs = rsqrtf(var + 1e-5f);
}

// --------------------------- graph preprocessing ---------------------------

__global__ void k_deg(const float* __restrict__ graph, float* __restrict__ d) {
  const int n = blockIdx.x;
  const int tid = threadIdx.x;
  float s = 0.f;
  const float* row = graph + (size_t)n * 2000;
  for (int m4 = tid; m4 < 500; m4 += 256) {
    const float4 g = *(const float4*)(row + m4 * 4);
    s += (g.x + g.y) + (g.z + g.w);
  }
  __shared__ float red[256];
  red[tid] = s;
  __syncthreads();
  for (int st = 128; st > 0; st >>= 1) {
    if (tid < st) red[tid] += red[tid + st];
    __syncthreads();
  }
  if (tid == 0) d[n] = rsqrtf(fmaxf(red[0] + 1.f, 1e-6f));
}

__global__ void k_lap(const float* __restrict__ graph, const float* __restrict__ d,
                      u16* __restrict__ L) {
  const int m = blockIdx.x * 1024 + threadIdx.x * 4;
  const int n = blockIdx.y;
  us4 r = {{0, 0, 0, 0}};
  if (n < 2000 && m < 2000) {
    const float4 g4 = *(const float4*)(graph + (size_t)n * 2000 + m);
    const float4 d4 = *(const float4*)(d + m);
    const float dn = d[n];
    const float gv[4] = {g4.x, g4.y, g4.z, g4.w};
    const float dv[4] = {d4.x, d4.y, d4.z, d4.w};
#pragma unroll
    for (int i = 0; i < 4; ++i) {
      const float delta = (n == m + i) ? 1.f : 0.f;
      r.v[i] = f2b(delta - dn * (gv[i] + delta) * dv[i]);
    }
  }
  *(us4*)(L + (size_t)n * 2048 + m) = r;
}

// --------------------------- input 1x1 conv (channel-major out) -------------
// h0T layout: [b][12][n:2048][c:64]; n in [2000,2048) zeroed (finite pad).
__global__ __launch_bounds__(256, 4)
void k_inconv(const float* __restrict__ x, const float* __restrict__ w,
              const float* __restrict__ bias, u16* __restrict__ h0T) {
  const int n0 = blockIdx.x * 64;
  const int b = blockIdx.y / 12, t = blockIdx.y % 12;
  const int tid = threadIdx.x;
  u16* outb = h0T + ((size_t)(b * 12 + t) * 2048 + n0) * 64;
  const float* xb = x + ((size_t)(b * 3) * 12 + t) * 2000;
#pragma unroll
  for (int q = 0; q < 4; ++q) {
    const int f = q * 256 + tid;       // flat us4 index in [0,1024)
    const int nl = f >> 4;             // local n 0..63
    const int c4 = (f & 15) * 4;       // channel base
    const int n = n0 + nl;
    us4 r = {{0, 0, 0, 0}};
    if (n < 2000) {
      const float a0 = xb[n];
      const float a1 = xb[12 * 2000 + n];
      const float a2 = xb[2 * 12 * 2000 + n];
#pragma unroll
      for (int j = 0; j < 4; ++j) {
        const int o = c4 + j;
        r.v[j] = f2b(a0 * w[o] + a1 * w[64 + o] + a2 * w[128 + o] + bias[o]);
      }
    }
    *(us4*)(outb + f * 4) = r;
  }
}

// --------------------------- weight fragment packing ------------------------
// grid (3, 8) -- 8-way slice of each mode's idx space (stride 2048).
__global__ void k_wpack(const float* __restrict__ t1w, const float* __restrict__ aw,
                        const float* __restrict__ th, const float* __restrict__ t2w,
                        u16* __restrict__ wglu, u16* __restrict__ wth,
                        u16* __restrict__ wt2, float* __restrict__ part2) {
  const int mode = blockIdx.x;
  const int start = blockIdx.y * 256 + threadIdx.x;
  if (mode == 0) {  // GLU: M=64, K=192, KS=6
    for (int idx = start; idx < 1536 * 8; idx += 2048) {
      int chunk = idx >> 3, j = idx & 7;
      int l15 = chunk & 15, quad = (chunk >> 4) & 3, g = chunk >> 6;
      int ks = g % 6, mi = g / 6;
      int o = mi * 16 + l15;
      int k = ks * 32 + quad * 8 + j;
      int c = k & 63, dt = k >> 6;
      float v = t1w[(o * 64 + c) * 3 + dt];
      if (o < 32 && dt == 2) v += aw[o * 64 + c];
      wglu[idx] = f2b(v);
    }
  } else if (mode == 1) {  // theta: M=32, K=96, KS=3 (padded to 512 chunks)
    if (blockIdx.y == 0) part2[threadIdx.x] = 0.f;  // zero LN partials
    for (int idx = start; idx < 512 * 8; idx += 2048) {
      int chunk = idx >> 3, j = idx & 7;
      int l15 = chunk & 15, quad = (chunk >> 4) & 3, g = chunk >> 6;
      float v = 0.f;
      if (g < 6) {
        int ks = g % 3, mi = g / 3;
        int o = mi * 16 + l15;
        int k = ks * 32 + quad * 8 + j;
        int i = k & 31, src = k >> 5;
        const float* p = th + (i * 32 + o) * 3;
        v = (src == 0) ? (p[0] - p[2]) : (src == 1 ? p[1] : 2.f * p[2]);
      }
      wth[idx] = f2b(v);
    }
  } else {  // t2: M=64, K=96, KS=3
    for (int idx = start; idx < 768 * 8; idx += 2048) {
      int chunk = idx >> 3, j = idx & 7;
      int l15 = chunk & 15, quad = (chunk >> 4) & 3, g = chunk >> 6;
      int ks = g % 3, mi = g / 3;
      int o = mi * 16 + l15;
      int k = ks * 32 + quad * 8 + j;
      int i = k & 31, dt = k >> 5;
      wt2[idx] = f2b(t2w[(o * 32 + i) * 3 + dt]);
    }
  }
}

// --------------------------- GLU MFMA kernel (R19a: upfront planes) ---------
// xT layout [b][T_in][2048][64]. All TCNT+2 planes loaded to registers once
// (2*(TCNT+2) short8); pure compute loop; raw lgkm barriers so the output
// stores never get drained by a barrier.
template <int TCNT>
__global__ __launch_bounds__(256, 3)
void k_mixT(const u16* __restrict__ xT, const u16* __restrict__ wp,
            const float* __restrict__ b0, const float* __restrict__ b1,
            u16* __restrict__ out, int T_in, int T) {
  __shared__ __align__(16) u16 lw[1536 * 8];   // 24 KB GLU A-frags
  __shared__ __align__(16) u16 lo[2][32][72];  // 9.2 KB output turn-around
  const int tid = threadIdx.x;
  const int lane = tid & 63, wave = tid >> 6;
  const int quad = lane >> 4, l15 = lane & 15;
  const int n0 = blockIdx.x * 64;
  const int b = blockIdx.y;
  const int t0 = blockIdx.z * TCNT;

#pragma unroll
  for (int p = 0; p < 6; ++p)
    gl_lds16(wp + (size_t)(p * 256 + wave * 64 + lane) * 8,
             &lw[(p * 256 + wave * 64) * 8]);

  float svb[8], gtb[8];
#pragma unroll
  for (int mi = 0; mi < 2; ++mi)
#pragma unroll
    for (int r = 0; r < 4; ++r) {
      const int i = mi * 16 + quad * 4 + r;
      svb[mi * 4 + r] = b0[i] + b1[i];
      gtb[mi * 4 + r] = b0[32 + i];
    }

  const int n = n0 + wave * 16 + l15;
  const size_t PL = (size_t)2048 * 64;   // plane stride
  const u16* px = xT + ((size_t)(b * T_in + t0) * 2048 + n) * 64 + quad * 8;

  // upfront: ALL planes t0 .. t0+TCNT+1 -> registers (one latency exposure)
  short8 f[2 * (TCNT + 2)];
#pragma unroll
  for (int p = 0; p < TCNT + 2; ++p) {
    f[2 * p]     = *(const short8*)(px + (size_t)p * PL);
    f[2 * p + 1] = *(const short8*)(px + (size_t)p * PL + 32);
  }

  // readback indices (per thread): channel tid>>3, n-octet (tid&7)*8
  const int rch = tid >> 3;
  const int rn8 = (tid & 7) * 8;

  asm volatile("s_waitcnt vmcnt(0)" ::: "memory");   // weight DMAs + planes
  __syncthreads();

#pragma unroll
  for (int tt = 0; tt < TCNT; ++tt) {
    const int t = t0 + tt;
    floatx4 acc[4] = {};
#pragma unroll
    for (int ks = 0; ks < 6; ++ks)
#pragma unroll
      for (int mi = 0; mi < 4; ++mi) {
        short8 afr = *(const short8*)&lw[((mi * 6 + ks) * 64 + lane) * 8];
        acc[mi] = __builtin_amdgcn_mfma_f32_16x16x32_bf16(
            afr, f[2 * tt + ks], acc[mi], 0, 0, 0);
      }

    // GLU epilogue -> LDS tile
    u16(*lob)[72] = lo[tt & 1];
#pragma unroll
    for (int mi = 0; mi < 2; ++mi)
#pragma unroll
      for (int r = 0; r < 4; ++r) {
        const int i = mi * 16 + quad * 4 + r;
        const float sv = acc[mi][r] + svb[mi * 4 + r];
        const float gt = acc[mi + 2][r] + gtb[mi * 4 + r];
        const float val = sv / (1.f + __expf(-gt));
        lob[i][wave * 16 + l15] = f2b(val);
      }
    // raw barrier: lob visible; in-flight global stores NOT drained
    asm volatile("s_waitcnt lgkmcnt(0)" ::: "memory");
    asm volatile("s_barrier" ::: "memory");

    // coalesced store: 8 lanes/channel -> 128B contiguous, line-aligned
    *(short8*)(out + (size_t)((b * 32 + rch) * T + t) * 2048 + n0 + rn8) =
        *(const short8*)&lob[rch][rn8];
  }
}

// --------------------------- fused theta + t2 kernel ------------------------
// R18-exact (R19b reverted): theta loop = plain runtime for, two
// __syncthreads per iter, serial loadrv -> repack. t2 phase keeps R17's
// drain-free raw barriers + register LN accumulation.
template <int TG, int TO>
__global__ __launch_bounds__(256, 2)
void k_mix12(const u16* __restrict__ x0, const u16* __restrict__ y1,
             const u16* __restrict__ y2, const u16* __restrict__ wth,
             const u16* __restrict__ wt2, const float* __restrict__ sb,
             const float* __restrict__ t2b, u16* __restrict__ out,
             float* __restrict__ part2) {
  __shared__ __align__(16) u16 lw1[512 * 8];        //  8 KB theta A-frags
  __shared__ __align__(16) u16 lw2[768 * 8];        // 12 KB t2 A-frags
  __shared__ __align__(16) u16 lx[780 * 8];         // 12 KB staging / t2-out
  __shared__ __align__(16) u16 lt[10 * 260 * 8];    // 41 KB theta-out ring
  __shared__ float redf[4][2 * TO];

  const int tid = threadIdx.x;
  const int lane = tid & 63, wave = tid >> 6;
  const int quad = lane >> 4, l15 = lane & 15;
  const int n0 = blockIdx.x * 64;
  const int b = blockIdx.y;
  const int n = n0 + wave * 16 + l15;

#pragma unroll
  for (int p = 0; p < 2; ++p)
    gl_lds16(wth + (size_t)(p * 256 + wave * 64 + lane) * 8,
             &lw1[(p * 256 + wave * 64) * 8]);
#pragma unroll
  for (int p = 0; p < 3; ++p)
    gl_lds16(wt2 + (size_t)(p * 256 + wave * 64 + lane) * 8,
             &lw2[(p * 256 + wave * 64) * 8]);

  const int nloc = (tid & 15) * 4;      // TPR=16
  const int g16 = tid >> 4;             // 0..15 row-groups per pass

  for (int t = 0; t < TG; ++t) {
    __syncthreads();  // lx free (prev theta done), lw DMAs drained (1st iter)
    us4 rv[2][4];
#pragma unroll
    for (int p = 0; p < 2; ++p) {
      const int k4 = p * 16 + g16;
      if (k4 < 24) {
#pragma unroll
        for (int i = 0; i < 4; ++i) {
          const int k = k4 * 4 + i;
          const u16* base = (k < 32) ? x0 : ((k < 64) ? y1 : y2);
          rv[p][i] = *(const us4*)(base +
              (size_t)((b * 32 + (k & 31)) * TG + t) * 2048 + n0 + nloc);
        }
      }
    }
#pragma unroll
    for (int p = 0; p < 2; ++p) {
      const int k4 = p * 16 + g16;
      if (k4 < 24) {
        const int ks = k4 >> 3, q8 = k4 & 7;
        const int quadw = (q8 >> 1) & 3;
        const int j0 = (q8 & 1) * 4;
#pragma unroll
        for (int i = 0; i < 4; ++i) {
          const int nn = nloc + i;
          const int chunk = (ks * 4 + (nn >> 4)) * 65 + quadw * 16 + (nn & 15);
          us4 wv;
          wv.v[0] = rv[p][0].v[i]; wv.v[1] = rv[p][1].v[i];
          wv.v[2] = rv[p][2].v[i]; wv.v[3] = rv[p][3].v[i];
          *(us4*)&lx[chunk * 8 + j0] = wv;
        }
      }
    }
    __syncthreads();

    floatx4 acc[2] = {};
#pragma unroll
    for (int ks = 0; ks < 3; ++ks) {
      short8 bfr = *(const short8*)&lx[((ks * 4 + wave) * 65 + lane) * 8];
#pragma unroll
      for (int mi = 0; mi < 2; ++mi) {
        short8 afr = *(const short8*)&lw1[((mi * 3 + ks) * 64 + lane) * 8];
        acc[mi] = __builtin_amdgcn_mfma_f32_16x16x32_bf16(afr, bfr, acc[mi], 0, 0, 0);
      }
    }
#pragma unroll
    for (int mi = 0; mi < 2; ++mi)
#pragma unroll
      for (int r = 0; r < 4; ++r) {
        const int o = mi * 16 + quad * 4 + r;
        const float v = acc[mi][r] + sb[o] +
            b2f(lx[(wave * 65 + ((o >> 3) & 3) * 16 + l15) * 8 + (o & 7)]);
        lt[((t * 4 + wave) * 65 + ((o >> 3) & 3) * 16 + l15) * 8 + (o & 7)] =
            f2b(fmaxf(v, 0.f));
      }
  }
  __syncthreads();  // theta done: lt complete, lx reads retired -> lo reuse

  u16(*lo)[72] = (u16(*)[72])lx;        // reuse lx: 64 x 72 = 4608 <= 6240
  float sAcc[TO], ssAcc[TO];
#pragma unroll
  for (int to = 0; to < TO; ++to) { sAcc[to] = 0.f; ssAcc[to] = 0.f; }

#pragma unroll
  for (int to = 0; to < TO; ++to) {
    floatx4 acc[4] = {};
#pragma unroll
    for (int ks = 0; ks < 3; ++ks) {
      short8 bfr = *(const short8*)&lt[(((to + ks) * 4 + wave) * 65 + lane) * 8];
#pragma unroll
      for (int mi = 0; mi < 4; ++mi) {
        short8 afr = *(const short8*)&lw2[((mi * 3 + ks) * 64 + lane) * 8];
        acc[mi] = __builtin_amdgcn_mfma_f32_16x16x32_bf16(afr, bfr, acc[mi], 0, 0, 0);
      }
    }
    // epilogue -> LDS tile + in-register LN partial sums (rounded values)
#pragma unroll
    for (int mi = 0; mi < 4; ++mi)
#pragma unroll
      for (int r = 0; r < 4; ++r) {
        const int o = mi * 16 + quad * 4 + r;
        float v = acc[mi][r] + t2b[o];
        if (o < 32)
          v += b2f(lt[(((to + 2) * 4 + wave) * 65 +
                       ((o >> 3) & 3) * 16 + l15) * 8 + (o & 7)]);
        const u16 hv = f2b(fmaxf(v, 0.f));
        lo[o][wave * 16 + l15] = hv;
        if (n < 2000) {
          const float vq = b2f(hv);
          sAcc[to] += vq; ssAcc[to] += vq * vq;
        }
      }
    // B1: lo visible to all waves (LDS only -- global stores NOT drained)
    asm volatile("s_waitcnt lgkmcnt(0)" ::: "memory");
    asm volatile("s_barrier" ::: "memory");

    // coalesced store: 2 short8 per thread, 128B contiguous per channel row
#pragma unroll
    for (int q = 0; q < 2; ++q) {
      const int f = q * 256 + tid;
      const int ch = f >> 3;
      const int n8 = (f & 7) * 8;
      if (n0 + n8 < 2000)   // 2000 % 8 == 0: short8 fully in or out
        *(short8*)(out + (size_t)((b * 64 + ch) * TO + to) * 2000 + n0 + n8) =
            *(const short8*)&lo[ch][n8];
    }
    // B2: lo reads retired (lgkm) before next iter overwrites; stores fly on
    asm volatile("s_waitcnt lgkmcnt(0)" ::: "memory");
    asm volatile("s_barrier" ::: "memory");
  }

  // final LN reduction: wave shuffle -> LDS -> one atomicAdd per (to,comp)
#pragma unroll
  for (int to = 0; to < TO; ++to) {
    float s = sAcc[to], ss = ssAcc[to];
#pragma unroll
    for (int off = 32; off > 0; off >>= 1) {
      s += __shfl_down(s, off);
      ss += __shfl_down(ss, off);
    }
    if (lane == 0) { redf[wave][to * 2] = s; redf[wave][to * 2 + 1] = ss; }
  }
  __syncthreads();
  if (tid < 2 * TO) {
    atomicAdd(&part2[(b * TO + (tid >> 1)) * 2 + (tid & 1)],
              redf[0][tid] + redf[1][tid] + redf[2][tid] + redf[3][tid]);
  }
}

// --------------------------- bf16 MFMA GEMM (C = A * Bt^T) ------------------
// R10 FROZEN.
template <int BM, int MPAD, int DPW>
__global__ __launch_bounds__(512, 1)
void k_gemm(const u16* __restrict__ A, const u16* __restrict__ Bt,
            u16* __restrict__ C) {
  constexpr int K = 2048;
  constexpr int NTI = K / 64;      // 32 K-tiles
  constexpr int AFR = BM / 32;     // A frags per wave (5 or 3)
  constexpr int WM = BM / 2;       // wave M extent (80 or 48)
  constexpr int S1 = (AFR + 1) / 2;
  constexpr int C1 = DPW - 4;      // tail chunk (3 or 2)
  constexpr int BROWS = 512;       // 2 ksub * 256 B-rows
  constexpr int ROWS = BROWS + 2 * MPAD;
  __shared__ __align__(16) u16 lds[2][ROWS * 32];

  const int tid = threadIdx.x;
  const int lane = tid & 63, wave = tid >> 6;
  const int quad = lane >> 4, l15 = lane & 15;
  const int m0 = blockIdx.y * BM, n0 = blockIdx.x * 256;
  const int wy = wave >> 2, wx = wave & 3;

  const int lr = lane >> 2;
  const int qv = (((lane & 3) - (lr + (lr >> 2))) & 3);
  const u16* sp[DPW];
  int dofs[DPW];
#pragma unroll
  for (int d = 0; d < DPW; ++d) {
    const int f = wave * DPW + d;
    if (f < 32) {  // B entry
      const int rb = f >> 1, ks = f & 1;
      sp[d] = Bt + (size_t)(n0 + rb * 16 + lr) * K + ks * 32 + qv * 8;
      dofs[d] = (ks * 256 + rb * 16) * 32;
    } else {       // A entry
      const int g = f - 32;
      const int rb = g >> 1, ks = g & 1;
      sp[d] = A + (size_t)(m0 + rb * 16 + lr) * K + ks * 32 + qv * 8;
      dofs[d] = (BROWS + ks * MPAD + rb * 16) * 32;
    }
  }

  const int sigr = (l15 + (l15 >> 2)) & 3;
  const int cofs = ((quad + sigr) & 3) * 8;

  floatx4 acc[AFR][4] = {};

#pragma unroll
  for (int d = 0; d < DPW; ++d) gl_lds16(sp[d], &lds[0][dofs[d]]);
#pragma unroll
  for (int d = 0; d < C1; ++d) gl_lds16(sp[d] + 64, &lds[1][dofs[d]]);
  if constexpr (C1 == 3) asm volatile("s_waitcnt vmcnt(3)" ::: "memory");
  else                   asm volatile("s_waitcnt vmcnt(2)" ::: "memory");
  asm volatile("s_barrier" ::: "memory");

  for (int it = 0; it < NTI; ++it) {
    const u16* cb = lds[it & 1];
    u16* nb = lds[(it & 1) ^ 1];
    u16* pb = lds[it & 1];
    const int kn1 = (it + 1) * 64;
    const bool st1 = (it + 1 < NTI);
    short8 bf[4], af[AFR];

    // ---- P1: ksub0, mi [0,S1) ----
#pragma unroll
    for (int ni = 0; ni < 4; ++ni)
      bf[ni] = *(const short8*)&cb[(wx * 64 + ni * 16 + l15) * 32 + cofs];
#pragma unroll
    for (int mi = 0; mi < S1; ++mi)
      af[mi] = *(const short8*)&cb[(BROWS + wy * WM + mi * 16 + l15) * 32 + cofs];
    if (st1) {
      gl_lds16(sp[C1] + kn1, &nb[dofs[C1]]);
      gl_lds16(sp[C1 + 1] + kn1, &nb[dofs[C1 + 1]]);
    }
#pragma unroll
    for (int mi = 0; mi < S1; ++mi)
#pragma unroll
      for (int ni = 0; ni < 4; ++ni)
        acc[mi][ni] = __builtin_amdgcn_mfma_f32_16x16x32_bf16(
            af[mi], bf[ni], acc[mi][ni], 0, 0, 0);

    // ---- P2: ksub0, mi [S1,AFR) ----
#pragma unroll
    for (int mi = S1; mi < AFR; ++mi)
      af[mi] = *(const short8*)&cb[(BROWS + wy * WM + mi * 16 + l15) * 32 + cofs];
    if (st1) {
      gl_lds16(sp[C1 + 2] + kn1, &nb[dofs[C1 + 2]]);
      gl_lds16(sp[C1 + 3] + kn1, &nb[dofs[C1 + 3]]);
    }
#pragma unroll
    for (int mi = S1; mi < AFR; ++mi)
#pragma unroll
      for (int ni = 0; ni < 4; ++ni)
        acc[mi][ni] = __builtin_amdgcn_mfma_f32_16x16x32_bf16(
            af[mi], bf[ni], acc[mi][ni], 0, 0, 0);

    // ---- P3: ksub1, mi [0,S1) ----
#pragma unroll
    for (int ni = 0; ni < 4; ++ni)
      bf[ni] = *(const short8*)&cb[(256 + wx * 64 + ni * 16 + l15) * 32 + cofs];
#pragma unroll
    for (int mi = 0; mi < S1; ++mi)
      af[mi] = *(const short8*)&cb[(BROWS + MPAD + wy * WM + mi * 16 + l15) * 32 + cofs];
#pragma unroll
    for (int mi = 0; mi < S1; ++mi)
#pragma unroll
      for (int ni = 0; ni < 4; ++ni)
        acc[mi][ni] = __builtin_amdgcn_mfma_f32_16x16x32_bf16(
            af[mi], bf[ni], acc[mi][ni], 0, 0, 0);

    // ---- P4: ksub1, mi [S1,AFR) ----
#pragma unroll
    for (int mi = S1; mi < AFR; ++mi)
      af[mi] = *(const short8*)&cb[(BROWS + MPAD + wy * WM + mi * 16 + l15) * 32 + cofs];
#pragma unroll
    for (int mi = S1; mi < AFR; ++mi)
#pragma unroll
      for (int ni = 0; ni < 4; ++ni)
        acc[mi][ni] = __builtin_amdgcn_mfma_f32_16x16x32_bf16(
            af[mi], bf[ni], acc[mi][ni], 0, 0, 0);

    // ---- tail: free cb, prefetch chunk1(it+2), retire tile it+1 ----
    asm volatile("s_waitcnt lgkmcnt(0)" ::: "memory");
    asm volatile("s_barrier" ::: "memory");
    if (it + 2 < NTI) {
      const int kn2 = (it + 2) * 64;
#pragma unroll
      for (int d = 0; d < C1; ++d) gl_lds16(sp[d] + kn2, &pb[dofs[d]]);
      if constexpr (C1 == 3) asm volatile("s_waitcnt vmcnt(3)" ::: "memory");
      else                   asm volatile("s_waitcnt vmcnt(2)" ::: "memory");
    } else {
      asm volatile("s_waitcnt vmcnt(0)" ::: "memory");
    }
    asm volatile("s_barrier" ::: "memory");
  }

#pragma unroll
  for (int mi = 0; mi < AFR; ++mi) {
#pragma unroll
    for (int ni = 0; ni < 4; ++ni) {
      const int row = m0 + wy * WM + mi * 16 + quad * 4;
      const int col = n0 + wx * 64 + ni * 16 + l15;
#pragma unroll
      for (int r = 0; r < 4; ++r)
        C[(size_t)(row + r) * K + col] = f2b(acc[mi][ni][r]);
    }
  }
}

// --------------------------- LayerNorm --------------------------------------

// LN-apply + transpose to channel-major: h [b,c,T,2000] -> hT [b,T,2048,64].
// Stats computed inline from part2 (k_lnfin folded in).
__global__ __launch_bounds__(256, 4)
void k_lnapT(const u16* __restrict__ h, const float* __restrict__ part2,
             const float* __restrict__ gw, const float* __restrict__ gb,
             u16* __restrict__ hT, int T) {
  __shared__ u16 tile[64][72];
  const int tid = threadIdx.x;
  const int n0 = blockIdx.x * 64;
  const int bt = blockIdx.y;           // b*T + t
  const int b = bt / T, t = bt % T;
  float mu, rs;
  ln_stats(part2, bt, mu, rs);

  {  // coalesced read: thread -> (c = tid>>2, 16 n's)
    const int c = tid >> 2;
    const int nq = (tid & 3) * 16;
    const u16* row = h + (size_t)((b * 64 + c) * T + t) * 2000 + n0 + nq;
#pragma unroll
    for (int k = 0; k < 4; ++k) {
      const us4 v = load4_guard(row + k * 4, n0 + nq + k * 4);
      *(us4*)&tile[c][nq + k * 4] = v;
    }
  }
  __syncthreads();

  // coalesced write: thread -> (n = tid>>2, 16 c's)
  const int n = tid >> 2;
  const int c0 = (tid & 3) * 16;
  const int gn = n0 + n;
  u16* dst = hT + ((size_t)(b * T + t) * 2048 + gn) * 64 + c0;
  if (gn >= 2000) {
    const us4 z = {{0, 0, 0, 0}};
#pragma unroll
    for (int q = 0; q < 4; ++q) *(us4*)(dst + q * 4) = z;
    return;
  }
#pragma unroll
  for (int q = 0; q < 4; ++q) {
    us4 r;
#pragma unroll
    for (int j = 0; j < 4; ++j) {
      const int cc = c0 + q * 4 + j;
      const float gv = gw[(size_t)gn * 64 + cc];
      const float bv = gb[(size_t)gn * 64 + cc];
      r.v[j] = f2b((b2f(tile[cc][n]) - mu) * rs * gv + bv);
    }
    *(us4*)(dst + q * 4) = r;
  }
}

// transpose gamma/beta [2000,64] -> [64,2048] (pad zeros) -- blk1 f32 path
__global__ void k_lngbT(const float* __restrict__ gw, const float* __restrict__ gb,
                        float* __restrict__ gwT, float* __restrict__ gbT) {
  const int n = blockIdx.x * 256 + threadIdx.x;
  const int c = blockIdx.y;
  float vw = 0.f, vb = 0.f;
  if (n < 2000) {
    vw = gw[(size_t)n * 64 + c];
    vb = gb[(size_t)n * 64 + c];
  }
  gwT[(size_t)c * 2048 + n] = vw;
  gbT[(size_t)c * 2048 + n] = vb;
}

// final f32 output LN-apply (blk1 only). Stats inline from part2.
__global__ void k_lnapply(const u16* __restrict__ h, const float* __restrict__ part2,
                          const float* __restrict__ gwT, const float* __restrict__ gbT,
                          float* __restrict__ outf, int T) {
  const int n = blockIdx.x * 1024 + threadIdx.x * 4;
  if (n >= 2000) return;
  int by = blockIdx.y;
  const int t = by % T; by /= T;
  const int c = by & 63;
  const int b = by >> 6;
  float mu, rs;
  ln_stats(part2, b * T + t, mu, rs);
  const size_t row = (size_t)((b * 64 + c) * T + t) * 2000 + n;
  const us4 hv = *(const us4*)(h + row);
  const float4 w4 = *(const float4*)(gwT + (size_t)c * 2048 + n);
  const float4 b4 = *(const float4*)(gbT + (size_t)c * 2048 + n);
  const float o0 = (b2f(hv.v[0]) - mu) * rs * w4.x + b4.x;
  const float o1 = (b2f(hv.v[1]) - mu) * rs * w4.y + b4.y;
  const float o2 = (b2f(hv.v[2]) - mu) * rs * w4.z + b4.z;
  const float o3 = (b2f(hv.v[3]) - mu) * rs * w4.w + b4.w;
  *(float4*)(outf + row) = make_float4(o0, o1, o2, o3);
}

// --------------------------- launch -----------------------------------------

extern "C" void kernel_launch(void* const* d_in, const int* in_sizes, int n_in,
                              void* d_out, int out_size, void* d_ws, size_t ws_size,
                              hipStream_t stream) {
  const float* x     = (const float*)d_in[0];
  const float* graph = (const float*)d_in[1];
  const float* in_w  = (const float*)d_in[2];
  const float* in_b  = (const float*)d_in[3];

  char* ws = (char*)d_ws;
  size_t off = 0;
  auto alloc = [&](size_t bytes) -> void* {
    void* p = ws + off;
    off += (bytes + 255) & ~(size_t)255;
    return p;
  };
  float* dd    = (float*)alloc(2048 * 4);
  float* part2 = (float*)alloc(256 * 4);
  float* gwT   = (float*)alloc((size_t)64 * 2048 * 4);
  float* gbT   = (float*)alloc((size_t)64 * 2048 * 4);
  u16* wpg  = (u16*)alloc((size_t)1536 * 8 * 2);
  u16* wpt  = (u16*)alloc((size_t)512 * 8 * 2);
  u16* wp2  = (u16*)alloc((size_t)768 * 8 * 2);
  u16* L    = (u16*)alloc((size_t)2048 * 2048 * 2);
  u16* h0T  = (u16*)alloc((size_t)16 * 12 * 2048 * 64 * 2);  // channel-major
  u16* Xp   = (u16*)alloc((size_t)5120 * 2048 * 2);
  u16* Y1   = (u16*)alloc((size_t)5120 * 2048 * 2);
  u16* Y2   = (u16*)alloc((size_t)5120 * 2048 * 2);
  u16* h1   = (u16*)alloc((size_t)16 * 64 * 8 * 2000 * 2);
  u16* h1T  = h0T;  // reuse: h0T dead after blk0 k_mixT (needs 16*8*2048*64*2)
  if (off > ws_size) return;

  k_deg<<<dim3(2000), dim3(256), 0, stream>>>(graph, dd);
  k_lap<<<dim3(2, 2048), dim3(256), 0, stream>>>(graph, dd, L);
  k_inconv<<<dim3(32, 192), dim3(256), 0, stream>>>(x, in_w, in_b, h0T);

  for (int blk = 0; blk < 2; ++blk) {
    const int base = 4 + blk * 10;
    const float* t1w = (const float*)d_in[base + 0];
    const float* t1b = (const float*)d_in[base + 1];
    const float* aw  = (const float*)d_in[base + 2];
    const float* ab  = (const float*)d_in[base + 3];
    const float* th  = (const float*)d_in[base + 4];
    const float* sb  = (const float*)d_in[base + 5];
    const float* t2w = (const float*)d_in[base + 6];
    const float* t2b = (const float*)d_in[base + 7];
    const float* lng = (const float*)d_in[base + 8];
    const float* lnb = (const float*)d_in[base + 9];

    const int T_in = (blk == 0) ? 12 : 8;
    const int T_g  = T_in - 2;  // 10 / 6
    const int T_o  = T_g - 2;   // 8 / 4
    const u16* hinT = (blk == 0) ? h0T : h1T;

    k_wpack<<<dim3(3, 8), dim3(256), 0, stream>>>(t1w, aw, th, t2w, wpg, wpt,
                                                  wp2, part2);
    if (blk == 0) {
      k_mixT<5><<<dim3(32, 16, 2), dim3(256), 0, stream>>>(
          hinT, wpg, t1b, ab, Xp, T_in, T_g);
      // M = 5120 = 32 x 160
      k_gemm<160, 192, 7><<<dim3(8, 32), dim3(512), 0, stream>>>(Xp, L, Y1);
      k_gemm<160, 192, 7><<<dim3(8, 32), dim3(512), 0, stream>>>(Y1, L, Y2);
      k_mix12<10, 8><<<dim3(32, 16), dim3(256), 0, stream>>>(
          Xp, Y1, Y2, wpt, wp2, sb, t2b, h1, part2);
      // LN-apply + transpose -> channel-major input for blk1 (stats inline)
      k_lnapT<<<dim3(32, 16 * T_o), dim3(256), 0, stream>>>(
          h1, part2, lng, lnb, h1T, T_o);
    } else {
      k_mixT<3><<<dim3(32, 16, 2), dim3(256), 0, stream>>>(
          hinT, wpg, t1b, ab, Xp, T_in, T_g);
      // M = 3072 = 32 x 96
      k_gemm<96, 128, 6><<<dim3(8, 32), dim3(512), 0, stream>>>(Xp, L, Y1);
      k_gemm<96, 128, 6><<<dim3(8, 32), dim3(512), 0, stream>>>(Y1, L, Y2);
      k_mix12<6, 4><<<dim3(32, 16), dim3(256), 0, stream>>>(
          Xp, Y1, Y2, wpt, wp2, sb, t2b, h1, part2);
      k_lngbT<<<dim3(8, 64), dim3(256), 0, stream>>>(lng, lnb, gwT, gbT);
      k_lnapply<<<dim3(2, 16 * 64 * T_o), dim3(256), 0, stream>>>(
          h1, part2, gwT, gbT, (float*)d_out, T_o);
    }
  }
}